// Round 1
// baseline (4142.750 us; speedup 1.0000x reference)
//
#include <hip/hip_runtime.h>
#include <math.h>

#define BB   256
#define TT   2048
#define DZc  256
#define CLIPV 5.0f

__device__ __forceinline__ float softplus_f(float s) {
    return fmaxf(s, 0.0f) + log1pf(expf(-fabsf(s)));
}

__global__ __launch_bounds__(256, 1)
void plrnn_scan(const float* __restrict__ xin,   // (B,T,1)
                const float* __restrict__ z0,    // (B,DZ)
                const float* __restrict__ AW,    // (DZ,DZ)
                const float* __restrict__ h,     // (DZ)
                const float* __restrict__ Cw,    // (DZ,1)
                const float* __restrict__ Rw,    // (1,DZ)
                const float* __restrict__ Rb,    // (1)
                float* __restrict__ out)         // (B,T,1)
{
    __shared__ float R0[DZc];        // relu(z), ping
    __shared__ float R1[DZc];        // relu(z), pong
    __shared__ float xs[TT];         // 8 KB: input sequence for this batch
    __shared__ float yp[TT * 4];     // 32 KB: per-wave y partials

    const int tid  = threadIdx.x;
    const int b    = blockIdx.x;
    const int lane = tid & 63;
    const int wid  = tid >> 6;

    // ---- one-time: W row tid into registers (diag zeroed), params ----
    float4 w[64];
    const float* awrow = AW + tid * DZc;
    #pragma unroll
    for (int j4 = 0; j4 < 64; ++j4) {
        float4 v = *reinterpret_cast<const float4*>(awrow + j4 * 4);
        if (j4 * 4 + 0 == tid) v.x = 0.0f;
        if (j4 * 4 + 1 == tid) v.y = 0.0f;
        if (j4 * 4 + 2 == tid) v.z = 0.0f;
        if (j4 * 4 + 3 == tid) v.w = 0.0f;
        w[j4] = v;
    }
    const float a_i  = AW[tid * DZc + tid];
    const float h_i  = h[tid];
    const float cw_i = Cw[tid];
    const float rw_i = Rw[tid];

    // ---- one-time: preload input sequence for this batch (coalesced) ----
    #pragma unroll
    for (int k = 0; k < TT / 256; ++k)
        xs[tid + k * 256] = xin[b * TT + tid + k * 256];

    float z = z0[b * DZc + tid];
    R0[tid] = fmaxf(z, 0.0f);
    __syncthreads();

    // ---- the scan: one barrier per step (double-buffered relu(z)) ----
    auto step = [&](const float* __restrict__ rcur,
                    float* __restrict__ rnxt, int t) {
        float acc0 = 0.0f, acc1 = 0.0f, acc2 = 0.0f, acc3 = 0.0f;
        #pragma unroll
        for (int j4 = 0; j4 < 64; ++j4) {
            float4 rv = *reinterpret_cast<const float4*>(rcur + j4 * 4);
            acc0 = fmaf(rv.x, w[j4].x, acc0);
            acc1 = fmaf(rv.y, w[j4].y, acc1);
            acc2 = fmaf(rv.z, w[j4].z, acc2);
            acc3 = fmaf(rv.w, w[j4].w, acc3);
        }
        float zi = fmaf(a_i, z, (acc0 + acc1) + (acc2 + acc3));
        zi = fmaf(xs[t], cw_i, zi + h_i);
        zi = fminf(fmaxf(zi, -CLIPV), CLIPV);
        z = zi;
        rnxt[tid] = fmaxf(zi, 0.0f);
        // y partial: dot(z, Rw) within the wave
        float p = zi * rw_i;
        #pragma unroll
        for (int off = 32; off >= 1; off >>= 1)
            p += __shfl_xor(p, off, 64);
        if (lane == 0) yp[t * 4 + wid] = p;
        __syncthreads();
    };

    for (int t = 0; t < TT; t += 2) {
        step(R0, R1, t);
        step(R1, R0, t + 1);
    }

    // ---- epilogue: combine wave partials, softplus, coalesced store ----
    const float rb = Rb[0];
    #pragma unroll
    for (int k = 0; k < TT / 256; ++k) {
        int t = tid + k * 256;
        float4 v = *reinterpret_cast<const float4*>(&yp[t * 4]);
        out[b * TT + t] = softplus_f(v.x + v.y + v.z + v.w + rb);
    }
}

extern "C" void kernel_launch(void* const* d_in, const int* in_sizes, int n_in,
                              void* d_out, int out_size, void* d_ws, size_t ws_size,
                              hipStream_t stream) {
    const float* xin = (const float*)d_in[0];
    const float* z0v = (const float*)d_in[1];
    const float* AW  = (const float*)d_in[2];
    const float* hv  = (const float*)d_in[3];
    const float* Cw  = (const float*)d_in[4];
    const float* Rw  = (const float*)d_in[5];
    const float* Rb  = (const float*)d_in[6];
    float* out = (float*)d_out;
    plrnn_scan<<<BB, 256, 0, stream>>>(xin, z0v, AW, hv, Cw, Rw, Rb, out);
}

// Round 6
// 4091.385 us; speedup vs baseline: 1.0126x; 1.0126x over previous
//
#include <hip/hip_runtime.h>
#include <math.h>

#define BB   256
#define TT   2048
#define DZc  256
#define CLIPV 5.0f

__device__ __forceinline__ float softplus_f(float s) {
    return fmaxf(s, 0.0f) + log1pf(expf(-fabsf(s)));
}

__global__ __launch_bounds__(256, 1)
void plrnn_scan(const float* __restrict__ xin,   // (B,T,1)
                const float* __restrict__ z0,    // (B,DZ)
                const float* __restrict__ AW,    // (DZ,DZ)
                const float* __restrict__ h,     // (DZ)
                const float* __restrict__ Cw,    // (DZ,1)
                const float* __restrict__ Rw,    // (1,DZ)
                const float* __restrict__ Rb,    // (1)
                float* __restrict__ out)         // (B,T,1)
{
    __shared__ float R0[DZc];        // relu(z), ping
    __shared__ float R1[DZc];        // relu(z), pong
    __shared__ float xs[TT];         // 8 KB: input sequence for this batch
    __shared__ float yp[TT * 4];     // 32 KB: per-wave y partials

    const int tid  = threadIdx.x;
    const int b    = blockIdx.x;
    const int lane = tid & 63;
    const int wid  = tid >> 6;

    // ---- one-time: W row tid into registers (diag zeroed), params ----
    float4 w[64];
    const float* awrow = AW + tid * DZc;
    #pragma unroll
    for (int j4 = 0; j4 < 64; ++j4) {
        float4 v = *reinterpret_cast<const float4*>(awrow + j4 * 4);
        if (j4 * 4 + 0 == tid) v.x = 0.0f;
        if (j4 * 4 + 1 == tid) v.y = 0.0f;
        if (j4 * 4 + 2 == tid) v.z = 0.0f;
        if (j4 * 4 + 3 == tid) v.w = 0.0f;
        w[j4] = v;
    }
    // Pin W in VGPRs: asm output is opaque -> compiler cannot rematerialize
    // these from memory inside the t-loop; 256 floats stay live in the RF.
    #pragma unroll
    for (int j4 = 0; j4 < 64; ++j4) {
        asm volatile("" : "+v"(w[j4].x), "+v"(w[j4].y),
                          "+v"(w[j4].z), "+v"(w[j4].w));
    }

    const float a_i  = AW[tid * DZc + tid];
    const float h_i  = h[tid];
    const float cw_i = Cw[tid];
    const float rw_i = Rw[tid];

    // ---- one-time: preload input sequence for this batch (coalesced) ----
    #pragma unroll
    for (int k = 0; k < TT / 256; ++k)
        xs[tid + k * 256] = xin[b * TT + tid + k * 256];

    float z = z0[b * DZc + tid];
    R0[tid] = fmaxf(z, 0.0f);
    __syncthreads();

    // ---- the scan: one barrier per step (double-buffered relu(z)) ----
    auto step = [&](const float* __restrict__ rcur,
                    float* __restrict__ rnxt, int t) {
        float acc0 = 0.0f, acc1 = 0.0f, acc2 = 0.0f, acc3 = 0.0f;
        #pragma unroll
        for (int j4 = 0; j4 < 64; ++j4) {
            float4 rv = *reinterpret_cast<const float4*>(rcur + j4 * 4);
            acc0 = fmaf(rv.x, w[j4].x, acc0);
            acc1 = fmaf(rv.y, w[j4].y, acc1);
            acc2 = fmaf(rv.z, w[j4].z, acc2);
            acc3 = fmaf(rv.w, w[j4].w, acc3);
        }
        float zi = fmaf(a_i, z, (acc0 + acc1) + (acc2 + acc3));
        zi = fmaf(xs[t], cw_i, zi + h_i);
        zi = fminf(fmaxf(zi, -CLIPV), CLIPV);
        z = zi;
        rnxt[tid] = fmaxf(zi, 0.0f);
        // y partial: dot(z, Rw) within the wave
        float p = zi * rw_i;
        #pragma unroll
        for (int off = 32; off >= 1; off >>= 1)
            p += __shfl_xor(p, off, 64);
        if (lane == 0) yp[t * 4 + wid] = p;
        __syncthreads();
    };

    for (int t = 0; t < TT; t += 2) {
        step(R0, R1, t);
        step(R1, R0, t + 1);
    }

    // ---- epilogue: combine wave partials, softplus, coalesced store ----
    const float rb = Rb[0];
    #pragma unroll
    for (int k = 0; k < TT / 256; ++k) {
        int t = tid + k * 256;
        float4 v = *reinterpret_cast<const float4*>(&yp[t * 4]);
        out[b * TT + t] = softplus_f(v.x + v.y + v.z + v.w + rb);
    }
}

extern "C" void kernel_launch(void* const* d_in, const int* in_sizes, int n_in,
                              void* d_out, int out_size, void* d_ws, size_t ws_size,
                              hipStream_t stream) {
    const float* xin = (const float*)d_in[0];
    const float* z0v = (const float*)d_in[1];
    const float* AW  = (const float*)d_in[2];
    const float* hv  = (const float*)d_in[3];
    const float* Cw  = (const float*)d_in[4];
    const float* Rw  = (const float*)d_in[5];
    const float* Rb  = (const float*)d_in[6];
    float* out = (float*)d_out;
    plrnn_scan<<<BB, 256, 0, stream>>>(xin, z0v, AW, hv, Cw, Rw, Rb, out);
}

// Round 7
// 2879.957 us; speedup vs baseline: 1.4385x; 1.4206x over previous
//
#include <hip/hip_runtime.h>
#include <math.h>

#define BB    256
#define TT    2048
#define DZc   256
#define CLIPV 5.0f

__device__ __forceinline__ float softplus_f(float s) {
    return fmaxf(s, 0.0f) + log1pf(expf(-fabsf(s)));
}

// uniform broadcast of lane `l`'s value via v_readlane (SGPR result)
__device__ __forceinline__ float rl(float v, int l) {
    return __builtin_bit_cast(float,
        __builtin_amdgcn_readlane(__builtin_bit_cast(int, v), l));
}

// waves_per_eu(1,1): min=max=1 wave/SIMD -> VGPR budget 512, defeats the
// occupancy heuristic that capped us at 168 (=512/3, from 43KB LDS / 3 blocks).
__global__ __launch_bounds__(256)
__attribute__((amdgpu_waves_per_eu(1, 1)))
void plrnn_scan(const float* __restrict__ xin,   // (B,T,1)
                const float* __restrict__ z0,    // (B,DZ)
                const float* __restrict__ AW,    // (DZ,DZ)
                const float* __restrict__ h,     // (DZ)
                const float* __restrict__ Cw,    // (DZ,1)
                const float* __restrict__ Rw,    // (1,DZ)
                const float* __restrict__ Rb,    // (1)
                float* __restrict__ out)         // (B,T,1)
{
    __shared__ float part[4][DZc];   // [wave][row] column-block partials, 4KB
    __shared__ float xs[TT];         // 8KB input sequence
    __shared__ float yw[2][4];       // ping-pong per-wave y partials

    const int tid  = threadIdx.x;
    const int b    = blockIdx.x;
    const int l    = tid & 63;
    const int w    = tid >> 6;
    const int col0 = w * 64;         // this wave's column block

    // ---- one-time: W[4l..4l+3][col0..col0+63] into 256 registers, diag=0 ----
    float wv[4][64];
    #pragma unroll
    for (int i = 0; i < 4; ++i) {
        const int row = 4 * l + i;
        const float* src = AW + row * DZc + col0;
        #pragma unroll
        for (int q = 0; q < 16; ++q) {
            float4 v = *reinterpret_cast<const float4*>(src + 4 * q);
            const int c = col0 + 4 * q;
            if (c + 0 == row) v.x = 0.0f;
            if (c + 1 == row) v.y = 0.0f;
            if (c + 2 == row) v.z = 0.0f;
            if (c + 3 == row) v.w = 0.0f;
            wv[i][4*q+0] = v.x; wv[i][4*q+1] = v.y;
            wv[i][4*q+2] = v.z; wv[i][4*q+3] = v.w;
        }
    }
    // opaque pin: forbid remat of the W registers inside the t-loop
    #pragma unroll
    for (int i = 0; i < 4; ++i)
        #pragma unroll
        for (int c = 0; c < 64; c += 4)
            asm volatile("" : "+v"(wv[i][c]), "+v"(wv[i][c+1]),
                              "+v"(wv[i][c+2]), "+v"(wv[i][c+3]));

    const float a_i  = AW[tid * DZc + tid];
    const float h_i  = h[tid];
    const float cw_i = Cw[tid];
    const float rw_i = Rw[tid];
    const float rb   = Rb[0];

    #pragma unroll
    for (int k = 0; k < TT / 256; ++k)
        xs[tid + 256 * k] = xin[b * TT + tid + 256 * k];

    float z = z0[b * DZc + tid];
    float r = fmaxf(z, 0.0f);        // r for column tid lives in THIS lane
    __syncthreads();

    for (int t = 0; t < TT; ++t) {
        // ---- phase 1: partial matvec over this wave's 64 columns ----
        // r_j for j in [col0, col0+64) is in this wave's own lanes ->
        // v_readlane broadcast (SGPR operand of the fma), no LDS.
        float acc0 = 0.f, acc1 = 0.f, acc2 = 0.f, acc3 = 0.f;
        #pragma unroll
        for (int c = 0; c < 64; ++c) {
            const float rc = rl(r, c);
            acc0 = fmaf(wv[0][c], rc, acc0);
            acc1 = fmaf(wv[1][c], rc, acc1);
            acc2 = fmaf(wv[2][c], rc, acc2);
            acc3 = fmaf(wv[3][c], rc, acc3);
        }

        // thread 0: emit previous step's y while others crunch
        if (tid == 0 && t > 0) {
            const float* yy = yw[(t - 1) & 1];
            out[(size_t)b * TT + (t - 1)] =
                softplus_f(yy[0] + yy[1] + yy[2] + yy[3] + rb);
        }

        // rows 4l..4l+3 contiguous -> one b128 store of the partials
        float4 pw = make_float4(acc0, acc1, acc2, acc3);
        *reinterpret_cast<float4*>(&part[w][4 * l]) = pw;
        __syncthreads();

        // ---- phase 2: combine partials, z-update, y-partial ----
        float s  = part[0][tid] + part[1][tid] + part[2][tid] + part[3][tid];
        float zi = fmaf(a_i, z, s);
        zi = fmaf(xs[t], cw_i, zi + h_i);
        zi = fminf(fmaxf(zi, -CLIPV), CLIPV);
        z = zi;
        r = fmaxf(zi, 0.0f);

        float p = zi * rw_i;
        #pragma unroll
        for (int off = 32; off >= 1; off >>= 1)
            p += __shfl_xor(p, off, 64);
        if (l == 0) yw[t & 1][w] = p;
        __syncthreads();   // yw visible; part safe to overwrite next iter
    }

    if (tid == 0) {
        const float* yy = yw[(TT - 1) & 1];
        out[(size_t)b * TT + (TT - 1)] =
            softplus_f(yy[0] + yy[1] + yy[2] + yy[3] + rb);
    }
}

extern "C" void kernel_launch(void* const* d_in, const int* in_sizes, int n_in,
                              void* d_out, int out_size, void* d_ws, size_t ws_size,
                              hipStream_t stream) {
    const float* xin = (const float*)d_in[0];
    const float* z0v = (const float*)d_in[1];
    const float* AW  = (const float*)d_in[2];
    const float* hv  = (const float*)d_in[3];
    const float* Cw  = (const float*)d_in[4];
    const float* Rw  = (const float*)d_in[5];
    const float* Rb  = (const float*)d_in[6];
    float* out = (float*)d_out;
    plrnn_scan<<<BB, 256, 0, stream>>>(xin, z0v, AW, hv, Cw, Rw, Rb, out);
}

// Round 10
// 2401.336 us; speedup vs baseline: 1.7252x; 1.1993x over previous
//
#include <hip/hip_runtime.h>
#include <math.h>

#define BB    256
#define TT    2048
#define DZc   256
#define CLIPV 5.0f

__device__ __forceinline__ float softplus_f(float s) {
    return fmaxf(s, 0.0f) + log1pf(expf(-fabsf(s)));
}

// uniform broadcast of lane `l`'s value via v_readlane (VALU, no LDS)
__device__ __forceinline__ float rl(float v, int l) {
    return __builtin_bit_cast(float,
        __builtin_amdgcn_readlane(__builtin_bit_cast(int, v), l));
}

__global__ __launch_bounds__(256)
__attribute__((amdgpu_waves_per_eu(1, 1)))
void plrnn_scan(const float* __restrict__ xin,   // (B,T,1)
                const float* __restrict__ z0,    // (B,DZ)
                const float* __restrict__ AW,    // (DZ,DZ)
                const float* __restrict__ h,     // (DZ)
                const float* __restrict__ Cw,    // (DZ,1)
                const float* __restrict__ Rw,    // (1,DZ)
                const float* __restrict__ Rb,    // (1)
                float* __restrict__ out)         // (B,T,1)
{
    __shared__ float part[2][4][DZc]; // 8KB double-buffered matvec partials
    __shared__ float xs[TT];          // 8KB input sequence
    __shared__ float ypr[512][4];     // 8KB y ring: [t mod 512][wave]

    const int tid  = threadIdx.x;
    const int b    = blockIdx.x;
    const int l    = tid & 63;
    const int w    = tid >> 6;
    const int col0 = w * 64;          // this wave's column block

    // ---- one-time: W[4l..4l+3][col0..col0+63] into 256 registers, diag=0 ----
    float wv[4][64];
    #pragma unroll
    for (int i = 0; i < 4; ++i) {
        const int row = 4 * l + i;
        const float* src = AW + row * DZc + col0;
        #pragma unroll
        for (int q = 0; q < 16; ++q) {
            float4 v = *reinterpret_cast<const float4*>(src + 4 * q);
            const int c = col0 + 4 * q;
            if (c + 0 == row) v.x = 0.0f;
            if (c + 1 == row) v.y = 0.0f;
            if (c + 2 == row) v.z = 0.0f;
            if (c + 3 == row) v.w = 0.0f;
            wv[i][4*q+0] = v.x; wv[i][4*q+1] = v.y;
            wv[i][4*q+2] = v.z; wv[i][4*q+3] = v.w;
        }
    }
    // opaque pin: forbid remat of the W registers inside the t-loop
    #pragma unroll
    for (int i = 0; i < 4; ++i)
        #pragma unroll
        for (int c = 0; c < 64; c += 4)
            asm volatile("" : "+v"(wv[i][c]), "+v"(wv[i][c+1]),
                              "+v"(wv[i][c+2]), "+v"(wv[i][c+3]));

    const float a_i  = AW[tid * DZc + tid];
    const float h_i  = h[tid];
    const float cw_i = Cw[tid];
    const float rw_i = Rw[tid];
    const float rb   = Rb[0];

    #pragma unroll
    for (int k = 0; k < TT / 256; ++k)
        xs[tid + 256 * k] = xin[b * TT + tid + 256 * k];

    float z = z0[b * DZc + tid];
    float r = fmaxf(z, 0.0f);        // relu(z_t), lane-local
    float u = z * rw_i;              // z_t * Rw[tid], lane-local (for y)

    // iteration t: state z=z_t; computes z_{t+1}; emits y_{t-1}=z_t·Rw+...
    for (int t = 0; t < TT; ++t) {
        // ---- phase 1: 64-col partial matvec + y partial, all via readlane ----
        float acc0 = 0.f, acc1 = 0.f, acc2 = 0.f, acc3 = 0.f, yac = 0.f;
        #pragma unroll
        for (int c = 0; c < 64; ++c) {
            const float rc = rl(r, c);   // relu(z_t)[col0+c]
            const float uc = rl(u, c);   // z_t[col0+c]*Rw[col0+c]
            yac  = yac + uc;
            acc0 = fmaf(wv[0][c], rc, acc0);
            acc1 = fmaf(wv[1][c], rc, acc1);
            acc2 = fmaf(wv[2][c], rc, acc2);
            acc3 = fmaf(wv[3][c], rc, acc3);
        }
        if (l == 0 && t > 0) ypr[(t - 1) & 511][w] = yac;  // y_{t-1} partial

        *reinterpret_cast<float4*>(&part[t & 1][w][4 * l]) =
            make_float4(acc0, acc1, acc2, acc3);
        __syncthreads();                 // single barrier per step

        // ---- phase 2: combine partials, z-update ----
        const float* pp = &part[t & 1][0][0];
        float s_ = pp[tid] + pp[DZc + tid] + pp[2*DZc + tid] + pp[3*DZc + tid];
        float zi = fmaf(a_i, z, s_);
        zi = fmaf(xs[t], cw_i, zi + h_i);
        zi = fminf(fmaxf(zi, -CLIPV), CLIPV);
        z = zi;
        r = fmaxf(zi, 0.0f);
        u = zi * rw_i;

        // ---- amortized flush: 256 y's, coalesced, every 256 steps ----
        if ((t & 255) == 0 && t) {
            const int base = t - 256;
            const int slot = (base + tid) & 511;
            float4 yy = *reinterpret_cast<const float4*>(&ypr[slot][0]);
            out[(size_t)b * TT + base + tid] =
                softplus_f(yy.x + yy.y + yy.z + yy.w + rb);
        }
    }

    // ---- epilogue: y_{T-1} = z_T · Rw, then flush last 256 ----
    {
        float yac = 0.f;
        #pragma unroll
        for (int c = 0; c < 64; ++c) yac += rl(u, c);
        if (l == 0) ypr[(TT - 1) & 511][w] = yac;
    }
    __syncthreads();
    {
        const int base = TT - 256;
        const int slot = (base + tid) & 511;
        float4 yy = *reinterpret_cast<const float4*>(&ypr[slot][0]);
        out[(size_t)b * TT + base + tid] =
            softplus_f(yy.x + yy.y + yy.z + yy.w + rb);
    }
}

extern "C" void kernel_launch(void* const* d_in, const int* in_sizes, int n_in,
                              void* d_out, int out_size, void* d_ws, size_t ws_size,
                              hipStream_t stream) {
    const float* xin = (const float*)d_in[0];
    const float* z0v = (const float*)d_in[1];
    const float* AW  = (const float*)d_in[2];
    const float* hv  = (const float*)d_in[3];
    const float* Cw  = (const float*)d_in[4];
    const float* Rw  = (const float*)d_in[5];
    const float* Rb  = (const float*)d_in[6];
    float* out = (float*)d_out;
    plrnn_scan<<<BB, 256, 0, stream>>>(xin, z0v, AW, hv, Cw, Rw, Rb, out);
}